// Round 14
// baseline (298.309 us; speedup 1.0000x reference)
//
#include <hip/hip_runtime.h>
#include <hip/hip_bf16.h>
#include <math.h>
#include <string.h>

#define N_NODES 50000
#define N_EDGES 800000
#define NH 4
#define LSTR 68   // padded lalT stride (floats): head rows 272B apart -> conflict-free

typedef unsigned int u32;
typedef unsigned short u16;
typedef __attribute__((ext_vector_type(8))) short bf16x8;
typedef __attribute__((ext_vector_type(4))) float f32x4;
typedef __attribute__((ext_vector_type(2))) float f32x2;

__device__ __forceinline__ u32 pack_bf2(float a, float b) {
    __hip_bfloat162 h2 = __float22bfloat162_rn(make_float2(a, b));
    u32 r;
    memcpy(&r, &h2, 4);
    return r;
}
__device__ __forceinline__ f32x2 bf2_to_v2(u32 u) {
    f32x2 v;
    v.x = __uint_as_float(u << 16);
    v.y = __uint_as_float(u & 0xffff0000u);
    return v;
}
__device__ __forceinline__ short bf16r(float f) {
    __hip_bfloat16 h = __float2bfloat16(f);
    short s;
    memcpy(&s, &h, 2);
    return s;
}
// acc += broadcast(a.lo) * b   (VOP3P op_sel broadcast of src0 low register)
__device__ __forceinline__ void pkfma_lo(f32x2& acc, f32x2 a, f32x2 b) {
    asm("v_pk_fma_f32 %0, %1, %2, %0 op_sel:[0,0,0] op_sel_hi:[0,1,1]"
        : "+v"(acc) : "v"(a), "v"(b));
}
// acc += broadcast(a.hi) * b
__device__ __forceinline__ void pkfma_hi(f32x2& acc, f32x2 a, f32x2 b) {
    asm("v_pk_fma_f32 %0, %1, %2, %0 op_sel:[1,0,0] op_sel_hi:[1,1,1]"
        : "+v"(acc) : "v"(a), "v"(b));
}

__device__ __forceinline__ float wred_max(float v) {
#pragma unroll
    for (int o = 32; o > 0; o >>= 1) v = fmaxf(v, __shfl_xor(v, o));
    return v;
}
__device__ __forceinline__ float wred_sum(float v) {
#pragma unroll
    for (int o = 32; o > 0; o >>= 1) v += __shfl_xor(v, o);
    return v;
}

// ---------------- CSR build ----------------

__global__ void k_hist(const int* __restrict__ dst, int* __restrict__ deg) {
    int i = blockIdx.x * 256 + threadIdx.x;
    if (i < N_EDGES) atomicAdd(&deg[dst[i]], 1);
}

__global__ __launch_bounds__(1024) void k_scan1(const int* __restrict__ deg,
                                                int* __restrict__ offs,
                                                int* __restrict__ bsum) {
    __shared__ int tmp[1024];
    int b = blockIdx.x, t = threadIdx.x;
    int i = b * 1024 + t;
    int v = (i < N_NODES) ? deg[i] : 0;
    tmp[t] = v;
    __syncthreads();
    for (int off = 1; off < 1024; off <<= 1) {
        int add = (t >= off) ? tmp[t - off] : 0;
        __syncthreads();
        tmp[t] += add;
        __syncthreads();
    }
    if (i < N_NODES) offs[i] = tmp[t] - v;
    if (t == 1023) bsum[b] = tmp[t];
}

// wave-parallel exclusive scan of bsum (nb <= 64)
__global__ void k_scan2(int* __restrict__ bsum, int nb) {
    int t = threadIdx.x & 63;
    int v = (t < nb) ? bsum[t] : 0;
    int orig = v;
#pragma unroll
    for (int o = 1; o < 64; o <<= 1) {
        int u = __shfl_up(v, o);
        if (t >= o) v += u;
    }
    if (t < nb) bsum[t] = v - orig;
}

__global__ __launch_bounds__(1024) void k_scan3(int* __restrict__ offs,
                                                const int* __restrict__ bsum,
                                                int* __restrict__ cursor) {
    int b = blockIdx.x, t = threadIdx.x;
    int i = b * 1024 + t;
    if (i < N_NODES) {
        int o = offs[i] + bsum[b];
        offs[i] = o;
        cursor[i] = o;
    }
    if (b == 0 && t == 0) offs[N_NODES] = N_EDGES;
}

__global__ void k_scatter(const int* __restrict__ src, const int* __restrict__ dst,
                          int* __restrict__ cursor, int* __restrict__ csrc) {
    int i = blockIdx.x * 256 + threadIdx.x;
    if (i < N_EDGES) {
        int p = atomicAdd(&cursor[dst[i]], 1);
        csrc[p] = src[i];
    }
}

// ---------------- fused W pre-pack (all 3 layers, one dispatch) ----------------
__device__ __forceinline__ u16 pack_elem(const float* W, int i, int K, int NT, int NOUT) {
    int j = i & 7;
    int lane = (i >> 3) & 63;
    int rest = i >> 9;
    int nt = rest % NT;
    int kt = rest / NT;
    int k = kt * 32 + (lane >> 4) * 8 + j;
    int col = nt * 16 + (lane & 15);
    float v = (col < NOUT) ? W[(size_t)k * NOUT + col] : 0.f;
    return (u16)bf16r(v);
}
__device__ __forceinline__ u16 pack_elem3(const float* W, int i) {
    int j = i & 7;
    int lane = (i >> 3) & 63;
    int rest = i >> 9;
    int nt = rest % 12;
    int kt = rest / 12;
    int k = kt * 32 + (lane >> 4) * 8 + j;
    int col = nt * 16 + (lane & 15);
    int h = col / 48, d = col % 48;
    float v = (d < 47) ? W[(size_t)k * 188 + h * 47 + d] : 0.f;
    return (u16)bf16r(v);
}
__global__ void prep_all(const float* __restrict__ W1, const float* __restrict__ W2,
                         const float* __restrict__ W3, u16* __restrict__ wp1,
                         u16* __restrict__ wp2, u16* __restrict__ wp3) {
    int idx = blockIdx.x * 256 + threadIdx.x;
    if (idx < 32768) {
        wp1[idx] = pack_elem(W1, idx, 256, 8, 128);
    } else if (idx < 49152) {
        int i = idx - 32768;
        wp2[i] = pack_elem(W2, i, 128, 8, 128);
    } else if (idx < 73728) {
        int i = idx - 49152;
        wp3[i] = pack_elem3(W3, i);
    }
}

// ---------------- MFMA GEMM: feat(bf16,[N,NP]) = A @ W (+fused attn dots) ----------------
template <int K, int NOUT, int NP, bool AF32, bool DOTS, bool HEADPAD>
__global__ __launch_bounds__(256) void gemm_mfma(const void* __restrict__ Av,
                                                 const u16* __restrict__ Wp,
                                                 u16* __restrict__ feat,
                                                 const float* __restrict__ al,
                                                 const float* __restrict__ ar,
                                                 float* __restrict__ el,
                                                 float* __restrict__ er) {
    constexpr int NT = NP / 16;
    constexpr int KT = K / 32;
    int w = threadIdx.x >> 6, l = threadIdx.x & 63;
    int tile_m0 = blockIdx.x * 64 + w * 16;
    int c15 = l & 15;
    int rowA = tile_m0 + c15;
    if (rowA >= N_NODES) rowA = N_NODES - 1;
    int g = l >> 4;

    f32x4 acc[NT];
#pragma unroll
    for (int nt = 0; nt < NT; ++nt) acc[nt] = (f32x4){0.f, 0.f, 0.f, 0.f};

    for (int kt = 0; kt < KT; ++kt) {
        bf16x8 a;
        if constexpr (AF32) {
            const float* ap = (const float*)Av + (size_t)rowA * K + kt * 32 + g * 8;
            float4 f0 = *reinterpret_cast<const float4*>(ap);
            float4 f1 = *reinterpret_cast<const float4*>(ap + 4);
            a[0] = bf16r(f0.x); a[1] = bf16r(f0.y); a[2] = bf16r(f0.z); a[3] = bf16r(f0.w);
            a[4] = bf16r(f1.x); a[5] = bf16r(f1.y); a[6] = bf16r(f1.z); a[7] = bf16r(f1.w);
        } else {
            a = *reinterpret_cast<const bf16x8*>((const u16*)Av + (size_t)rowA * K + kt * 32 + g * 8);
        }
        const u16* wp = Wp + ((size_t)kt * NT) * 512 + (size_t)l * 8;
#pragma unroll
        for (int nt = 0; nt < NT; ++nt) {
            bf16x8 b = *reinterpret_cast<const bf16x8*>(wp + nt * 512);
            acc[nt] = __builtin_amdgcn_mfma_f32_16x16x32_bf16(a, b, acc[nt], 0, 0, 0);
        }
    }

    int rowD0 = tile_m0 + g * 4;
#pragma unroll
    for (int nt = 0; nt < NT; ++nt) {
        int col = nt * 16 + c15;
#pragma unroll
        for (int r = 0; r < 4; ++r) {
            int row = rowD0 + r;
            if (row < N_NODES)
                feat[(size_t)row * NP + col] = (u16)bf16r(acc[nt][r]);
        }
    }

    if constexpr (DOTS) {
        float alv[NT], arv[NT];
#pragma unroll
        for (int nt = 0; nt < NT; ++nt) {
            if constexpr (HEADPAD) {
                int h = nt / 3, m = nt % 3;
                if (m == 2) {
                    alv[nt] = (c15 < 15) ? al[h * 47 + 32 + c15] : 0.f;
                    arv[nt] = (c15 < 15) ? ar[h * 47 + 32 + c15] : 0.f;
                } else {
                    alv[nt] = al[h * 47 + m * 16 + c15];
                    arv[nt] = ar[h * 47 + m * 16 + c15];
                }
            } else {
                alv[nt] = al[nt * 16 + c15];
                arv[nt] = ar[nt * 16 + c15];
            }
        }
#pragma unroll
        for (int r = 0; r < 4; ++r) {
            float hlv[NH] = {0.f, 0.f, 0.f, 0.f};
            float hrv[NH] = {0.f, 0.f, 0.f, 0.f};
#pragma unroll
            for (int nt = 0; nt < NT; ++nt) {
                constexpr int NTH = NT / NH;
                int h = nt / NTH;
                hlv[h] = fmaf(acc[nt][r], alv[nt], hlv[h]);
                hrv[h] = fmaf(acc[nt][r], arv[nt], hrv[h]);
            }
#pragma unroll
            for (int o = 1; o < 16; o <<= 1) {
#pragma unroll
                for (int j = 0; j < NH; ++j) {
                    hlv[j] += __shfl_xor(hlv[j], o);
                    hrv[j] += __shfl_xor(hrv[j], o);
                }
            }
            int row = rowD0 + r;
            if (c15 == 0 && row < N_NODES) {
                *reinterpret_cast<float4*>(el + (size_t)row * NH) =
                    make_float4(hlv[0], hlv[1], hlv[2], hlv[3]);
                *reinterpret_cast<float4*>(er + (size_t)row * NH) =
                    make_float4(hrv[0], hrv[1], hrv[2], hrv[3]);
            }
        }
    }
}

// ---------------- per-chunk alpha -> LDS (transposed) + premultiplied row byte offsets ----
__device__ __forceinline__ void alpha_chunk_T(const float* __restrict__ el,
                                              const int* __restrict__ csrc,
                                              float4 erv, int base, int i1, u32 rowb,
                                              float4 mref, float4 vinv, bool online,
                                              float* __restrict__ lalT,
                                              u32* __restrict__ loff, int lane) {
    int e = base + lane;
    bool act = e < i1;
    int srcn = act ? csrc[e] : 0;
    float4 elv = make_float4(0.f, 0.f, 0.f, 0.f);
    if (act) elv = *reinterpret_cast<const float4*>(el + (size_t)srcn * NH);
    float e0 = elv.x + erv.x; e0 = e0 >= 0.f ? e0 : 0.2f * e0;
    float e1 = elv.y + erv.y; e1 = e1 >= 0.f ? e1 : 0.2f * e1;
    float e2 = elv.z + erv.z; e2 = e2 >= 0.f ? e2 : 0.2f * e2;
    float e3 = elv.w + erv.w; e3 = e3 >= 0.f ? e3 : 0.2f * e3;
    float4 a4;
    if (online) {
        const float NEG = -__builtin_inff();
        float f0 = act ? e0 : NEG, f1 = act ? e1 : NEG, f2 = act ? e2 : NEG, f3 = act ? e3 : NEG;
        float m0 = wred_max(f0), m1 = wred_max(f1), m2 = wred_max(f2), m3 = wred_max(f3);
        float p0 = act ? __expf(e0 - m0) : 0.f;
        float p1 = act ? __expf(e1 - m1) : 0.f;
        float p2 = act ? __expf(e2 - m2) : 0.f;
        float p3 = act ? __expf(e3 - m3) : 0.f;
        float s0 = wred_sum(p0), s1 = wred_sum(p1), s2 = wred_sum(p2), s3 = wred_sum(p3);
        a4 = make_float4(act ? p0 / s0 : 0.f, act ? p1 / s1 : 0.f,
                         act ? p2 / s2 : 0.f, act ? p3 / s3 : 0.f);
    } else {
        a4 = make_float4(act ? __expf(e0 - mref.x) * vinv.x : 0.f,
                         act ? __expf(e1 - mref.y) * vinv.y : 0.f,
                         act ? __expf(e2 - mref.z) * vinv.z : 0.f,
                         act ? __expf(e3 - mref.w) * vinv.w : 0.f);
    }
    lalT[0 * LSTR + lane] = a4.x;
    lalT[1 * LSTR + lane] = a4.y;
    lalT[2 * LSTR + lane] = a4.z;
    lalT[3 * LSTR + lane] = a4.w;
    loff[lane] = (u32)srcn * rowb;
}

// global-stats pass for deg>64 nodes
__device__ __forceinline__ void stats_pass(const float* __restrict__ el,
                                           const int* __restrict__ csrc,
                                           float4 erv, int i0, int i1, int lane,
                                           float4& mout, float4& vout) {
    const float NEG = -__builtin_inff();
    float m0 = NEG, m1 = NEG, m2 = NEG, m3 = NEG;
    float s0 = 0.f, s1 = 0.f, s2 = 0.f, s3 = 0.f;
    for (int base = i0; base < i1; base += 64) {
        int i = base + lane;
        bool act = i < i1;
        int srcn = act ? csrc[i] : 0;
        float4 elv = make_float4(0.f, 0.f, 0.f, 0.f);
        if (act) elv = *reinterpret_cast<const float4*>(el + (size_t)srcn * NH);
        float e0 = elv.x + erv.x; e0 = e0 >= 0.f ? e0 : 0.2f * e0;
        float e1 = elv.y + erv.y; e1 = e1 >= 0.f ? e1 : 0.2f * e1;
        float e2 = elv.z + erv.z; e2 = e2 >= 0.f ? e2 : 0.2f * e2;
        float e3 = elv.w + erv.w; e3 = e3 >= 0.f ? e3 : 0.2f * e3;
        if (!act) { e0 = NEG; e1 = NEG; e2 = NEG; e3 = NEG; }
        float c0 = wred_max(e0), c1 = wred_max(e1), c2 = wred_max(e2), c3 = wred_max(e3);
        float nm0 = fmaxf(m0, c0), nm1 = fmaxf(m1, c1), nm2 = fmaxf(m2, c2), nm3 = fmaxf(m3, c3);
        float p0 = act ? __expf(e0 - nm0) : 0.f;
        float p1 = act ? __expf(e1 - nm1) : 0.f;
        float p2 = act ? __expf(e2 - nm2) : 0.f;
        float p3 = act ? __expf(e3 - nm3) : 0.f;
        float S0 = wred_sum(p0), S1 = wred_sum(p1), S2 = wred_sum(p2), S3 = wred_sum(p3);
        s0 = s0 * __expf(m0 - nm0) + S0; m0 = nm0;
        s1 = s1 * __expf(m1 - nm1) + S1; m1 = nm1;
        s2 = s2 * __expf(m2 - nm2) + S2; m2 = nm2;
        s3 = s3 * __expf(m3 - nm3) + S3; m3 = nm3;
    }
    mout = make_float4(m0, m1, m2, m3);
    vout = make_float4(1.f / s0, 1.f / s1, 1.f / s2, 1.f / s3);
}

// ---------------- fused softmax+aggregation, layers 1-2 (128 cols) ----------------
// slice-cooperative: 16 lanes x dwordx4 = one 256B row; 4 edges per VMEM instr.
__global__ __launch_bounds__(256) void gat_agg128(const u16* __restrict__ feat,
                                                  const float* __restrict__ el,
                                                  const float* __restrict__ er,
                                                  const int* __restrict__ offs,
                                                  const int* __restrict__ csrc,
                                                  u16* __restrict__ out) {
    __shared__ float lalT[4][4][LSTR];
    __shared__ u32 loff[4][64];
    int wave = threadIdx.x >> 6;
    int lane = threadIdx.x & 63;
    int n = blockIdx.x * 4 + wave;
    int sub = lane >> 4, sl = lane & 15;
    int h = sl >> 2;                 // 8-col slice sl covers cols sl*8..+7; head = sl/4
    u32 soff = (u32)sl * 16u;        // byte offset of slice within row
    int i0 = offs[n], i1 = offs[n + 1];
    int d = i1 - i0;
    f32x2 acc0 = (f32x2){0.f, 0.f}, acc1 = acc0, acc2 = acc0, acc3 = acc0;
    if (d > 0) {
        float4 erv = *reinterpret_cast<const float4*>(er + (size_t)n * NH);
        float4 mref = make_float4(0.f, 0.f, 0.f, 0.f), vinv = mref;
        bool onechunk = d <= 64;
        if (!onechunk) stats_pass(el, csrc, erv, i0, i1, lane, mref, vinv);
        const char* fbase = (const char*)feat;
        for (int base = i0; base < i1; base += 64) {
            alpha_chunk_T(el, csrc, erv, base, i1, 256u, mref, vinv, onechunk,
                          &lalT[wave][0][0], &loff[wave][0], lane);
            int cnt = i1 - base; if (cnt > 64) cnt = 64;
            int cpad = (cnt + 7) & ~7;
            for (int j = 0; j < cpad; j += 8) {
                u32 o0 = loff[wave][j + sub] + soff;
                u32 o1 = loff[wave][j + 4 + sub] + soff;
                uint4 q0 = *reinterpret_cast<const uint4*>(fbase + o0);
                uint4 q1 = *reinterpret_cast<const uint4*>(fbase + o1);
                f32x2 ap = (f32x2){lalT[wave][h][j + sub], lalT[wave][h][j + 4 + sub]};
                pkfma_lo(acc0, ap, bf2_to_v2(q0.x));
                pkfma_lo(acc1, ap, bf2_to_v2(q0.y));
                pkfma_lo(acc2, ap, bf2_to_v2(q0.z));
                pkfma_lo(acc3, ap, bf2_to_v2(q0.w));
                pkfma_hi(acc0, ap, bf2_to_v2(q1.x));
                pkfma_hi(acc1, ap, bf2_to_v2(q1.y));
                pkfma_hi(acc2, ap, bf2_to_v2(q1.z));
                pkfma_hi(acc3, ap, bf2_to_v2(q1.w));
            }
        }
    }
    float v[8] = {acc0.x, acc0.y, acc1.x, acc1.y, acc2.x, acc2.y, acc3.x, acc3.y};
#pragma unroll
    for (int k = 0; k < 8; ++k) {
        v[k] += __shfl_xor(v[k], 16);
        v[k] += __shfl_xor(v[k], 32);
    }
    if (sub == 0) {
        float o[8];
#pragma unroll
        for (int k = 0; k < 8; ++k) o[k] = v[k] > 0.f ? v[k] : expm1f(v[k]);
        uint4 wv = make_uint4(pack_bf2(o[0], o[1]), pack_bf2(o[2], o[3]),
                              pack_bf2(o[4], o[5]), pack_bf2(o[6], o[7]));
        *reinterpret_cast<uint4*>(out + (size_t)n * 128 + sl * 8) = wv;
    }
}

// ---------------- fused softmax+aggregation, layer 3 (192-col head-major-48) ----------------
// slice-cooperative: 24-of-32 lanes x dwordx4 = one 384B row; 2 edges per VMEM instr.
// 48 cols/head = 6 slices of 8 -> each slice entirely within one head.
__global__ __launch_bounds__(256) void gat_agg_final(const u16* __restrict__ feat,
                                                     const float* __restrict__ el,
                                                     const float* __restrict__ er,
                                                     const int* __restrict__ offs,
                                                     const int* __restrict__ csrc,
                                                     float* __restrict__ out) {
    __shared__ float lalT[4][4][LSTR];
    __shared__ u32 loff[4][64];
    __shared__ float lds[4][192];
    int wave = threadIdx.x >> 6;
    int lane = threadIdx.x & 63;
    int n = blockIdx.x * 4 + wave;
    int sub = lane >> 5, sl = lane & 31;
    bool act = sl < 24;
    int h = act ? (sl / 6) : 0;      // 6 slices per 48-col head
    u32 soff = (u32)sl * 16u;
    int i0 = offs[n], i1 = offs[n + 1];
    int d = i1 - i0;
    f32x2 acc0 = (f32x2){0.f, 0.f}, acc1 = acc0, acc2 = acc0, acc3 = acc0;
    if (d > 0) {
        float4 erv = *reinterpret_cast<const float4*>(er + (size_t)n * NH);
        float4 mref = make_float4(0.f, 0.f, 0.f, 0.f), vinv = mref;
        bool onechunk = d <= 64;
        if (!onechunk) stats_pass(el, csrc, erv, i0, i1, lane, mref, vinv);
        const char* fbase = (const char*)feat;
        for (int base = i0; base < i1; base += 64) {
            alpha_chunk_T(el, csrc, erv, base, i1, 384u, mref, vinv, onechunk,
                          &lalT[wave][0][0], &loff[wave][0], lane);
            int cnt = i1 - base; if (cnt > 64) cnt = 64;
            int cpad = (cnt + 3) & ~3;
            if (act) {
                for (int j = 0; j < cpad; j += 4) {
                    u32 o0 = loff[wave][j + sub] + soff;
                    u32 o1 = loff[wave][j + 2 + sub] + soff;
                    uint4 q0 = *reinterpret_cast<const uint4*>(fbase + o0);
                    uint4 q1 = *reinterpret_cast<const uint4*>(fbase + o1);
                    f32x2 ap = (f32x2){lalT[wave][h][j + sub], lalT[wave][h][j + 2 + sub]};
                    pkfma_lo(acc0, ap, bf2_to_v2(q0.x));
                    pkfma_lo(acc1, ap, bf2_to_v2(q0.y));
                    pkfma_lo(acc2, ap, bf2_to_v2(q0.z));
                    pkfma_lo(acc3, ap, bf2_to_v2(q0.w));
                    pkfma_hi(acc0, ap, bf2_to_v2(q1.x));
                    pkfma_hi(acc1, ap, bf2_to_v2(q1.y));
                    pkfma_hi(acc2, ap, bf2_to_v2(q1.z));
                    pkfma_hi(acc3, ap, bf2_to_v2(q1.w));
                }
            }
        }
    }
    float v[8] = {acc0.x, acc0.y, acc1.x, acc1.y, acc2.x, acc2.y, acc3.x, acc3.y};
#pragma unroll
    for (int k = 0; k < 8; ++k) v[k] += __shfl_xor(v[k], 32);
    if (sub == 0 && act) {
        float4 lo = make_float4(v[0], v[1], v[2], v[3]);
        float4 hi = make_float4(v[4], v[5], v[6], v[7]);
        *reinterpret_cast<float4*>(&lds[wave][sl * 8]) = lo;
        *reinterpret_cast<float4*>(&lds[wave][sl * 8 + 4]) = hi;
    }
    __syncthreads();
    float u = (lane < 47)
                  ? 0.25f * (lds[wave][lane] + lds[wave][48 + lane] +
                             lds[wave][96 + lane] + lds[wave][144 + lane])
                  : -__builtin_inff();
    float mx = u;
#pragma unroll
    for (int o = 32; o > 0; o >>= 1) mx = fmaxf(mx, __shfl_xor(mx, o));
    float ex = (lane < 47) ? __expf(u - mx) : 0.f;
    float sm = ex;
#pragma unroll
    for (int o = 32; o > 0; o >>= 1) sm += __shfl_xor(sm, o);
    if (lane < 47) out[(size_t)n * 47 + lane] = u - mx - logf(sm);
}

// ---------------- launch ----------------

extern "C" void kernel_launch(void* const* d_in, const int* in_sizes, int n_in,
                              void* d_out, int out_size, void* d_ws, size_t ws_size,
                              hipStream_t stream) {
    const float* x = (const float*)d_in[0];
    const int* src = (const int*)d_in[1];
    const int* dst = (const int*)d_in[2];
    const float* W1 = (const float*)d_in[3];
    const float* al1 = (const float*)d_in[4];
    const float* ar1 = (const float*)d_in[5];
    const float* W2 = (const float*)d_in[6];
    const float* al2 = (const float*)d_in[7];
    const float* ar2 = (const float*)d_in[8];
    const float* W3 = (const float*)d_in[9];
    const float* al3 = (const float*)d_in[10];
    const float* ar3 = (const float*)d_in[11];
    float* out = (float*)d_out;

    char* p = (char*)d_ws;
    auto alloc = [&](size_t bytes) {
        char* r = p;
        p += (bytes + 255) & ~(size_t)255;
        return r;
    };
    u16* bufA = (u16*)alloc((size_t)N_NODES * 128 * 2);
    u16* bufC = (u16*)alloc((size_t)N_NODES * 128 * 2);
    u16* featb = (u16*)alloc((size_t)N_NODES * 192 * 2);
    float* el = (float*)alloc((size_t)N_NODES * NH * 4);
    float* er = (float*)alloc((size_t)N_NODES * NH * 4);
    u16* wp1 = (u16*)alloc((size_t)32768 * 2);
    u16* wp2 = (u16*)alloc((size_t)16384 * 2);
    u16* wp3 = (u16*)alloc((size_t)24576 * 2);
    int* deg = (int*)alloc((size_t)N_NODES * 4);
    int* offs = (int*)alloc((size_t)(N_NODES + 1) * 4);
    int* cursor = (int*)alloc((size_t)N_NODES * 4);
    int* bsum = (int*)alloc(64 * 4);
    int* csrc = (int*)alloc((size_t)N_EDGES * 4);

    // fused W pre-pack (one dispatch)
    prep_all<<<288, 256, 0, stream>>>(W1, W2, W3, wp1, wp2, wp3);

    // CSR by dst
    hipMemsetAsync(deg, 0, (size_t)N_NODES * 4, stream);
    k_hist<<<(N_EDGES + 255) / 256, 256, 0, stream>>>(dst, deg);
    k_scan1<<<49, 1024, 0, stream>>>(deg, offs, bsum);
    k_scan2<<<1, 64, 0, stream>>>(bsum, 49);
    k_scan3<<<49, 1024, 0, stream>>>(offs, bsum, cursor);
    k_scatter<<<(N_EDGES + 255) / 256, 256, 0, stream>>>(src, dst, cursor, csrc);

    int gemm_grid = (N_NODES + 63) / 64;
    // layer 1
    gemm_mfma<256, 128, 128, true, true, false><<<gemm_grid, 256, 0, stream>>>(x, wp1, featb, al1, ar1, el, er);
    gat_agg128<<<N_NODES / 4, 256, 0, stream>>>(featb, el, er, offs, csrc, bufA);
    // layer 2
    gemm_mfma<128, 128, 128, false, true, false><<<gemm_grid, 256, 0, stream>>>(bufA, wp2, featb, al2, ar2, el, er);
    gat_agg128<<<N_NODES / 4, 256, 0, stream>>>(featb, el, er, offs, csrc, bufC);
    // layer 3 (head-major-48 padded layout; dots fused)
    gemm_mfma<128, 192, 192, false, true, true><<<gemm_grid, 256, 0, stream>>>(bufC, wp3, featb, al3, ar3, el, er);
    gat_agg_final<<<N_NODES / 4, 256, 0, stream>>>(featb, el, er, offs, csrc, out);
}

// Round 15
// 294.682 us; speedup vs baseline: 1.0123x; 1.0123x over previous
//
#include <hip/hip_runtime.h>
#include <hip/hip_bf16.h>
#include <math.h>
#include <string.h>

#define N_NODES 50000
#define N_EDGES 800000
#define NH 4
#define LSTR 68   // padded lalT stride (floats): head rows 272B apart -> conflict-free

typedef unsigned int u32;
typedef unsigned short u16;
typedef __attribute__((ext_vector_type(8))) short bf16x8;
typedef __attribute__((ext_vector_type(4))) float f32x4;
typedef __attribute__((ext_vector_type(2))) float f32x2;

__device__ __forceinline__ u32 pack_bf2(float a, float b) {
    __hip_bfloat162 h2 = __float22bfloat162_rn(make_float2(a, b));
    u32 r;
    memcpy(&r, &h2, 4);
    return r;
}
__device__ __forceinline__ f32x2 bf2_to_v2(u32 u) {
    f32x2 v;
    v.x = __uint_as_float(u << 16);
    v.y = __uint_as_float(u & 0xffff0000u);
    return v;
}
__device__ __forceinline__ short bf16r(float f) {
    __hip_bfloat16 h = __float2bfloat16(f);
    short s;
    memcpy(&s, &h, 2);
    return s;
}
// acc += broadcast(a.lo) * b   (VOP3P op_sel broadcast of src0 low register)
__device__ __forceinline__ void pkfma_lo(f32x2& acc, f32x2 a, f32x2 b) {
    asm("v_pk_fma_f32 %0, %1, %2, %0 op_sel:[0,0,0] op_sel_hi:[0,1,1]"
        : "+v"(acc) : "v"(a), "v"(b));
}
// acc += broadcast(a.hi) * b
__device__ __forceinline__ void pkfma_hi(f32x2& acc, f32x2 a, f32x2 b) {
    asm("v_pk_fma_f32 %0, %1, %2, %0 op_sel:[1,0,0] op_sel_hi:[1,1,1]"
        : "+v"(acc) : "v"(a), "v"(b));
}

__device__ __forceinline__ float wred_max(float v) {
#pragma unroll
    for (int o = 32; o > 0; o >>= 1) v = fmaxf(v, __shfl_xor(v, o));
    return v;
}
__device__ __forceinline__ float wred_sum(float v) {
#pragma unroll
    for (int o = 32; o > 0; o >>= 1) v += __shfl_xor(v, o);
    return v;
}
__device__ __forceinline__ int wred_sum_i(int v) {
#pragma unroll
    for (int o = 32; o > 0; o >>= 1) v += __shfl_xor(v, o);
    return v;
}

// ---------------- CSR build ----------------

__global__ void k_hist(const int* __restrict__ dst, int* __restrict__ deg) {
    int i = blockIdx.x * 256 + threadIdx.x;
    if (i < N_EDGES) atomicAdd(&deg[dst[i]], 1);
}

__global__ __launch_bounds__(1024) void k_scan1(const int* __restrict__ deg,
                                                int* __restrict__ offs,
                                                int* __restrict__ bsum) {
    __shared__ int tmp[1024];
    int b = blockIdx.x, t = threadIdx.x;
    int i = b * 1024 + t;
    int v = (i < N_NODES) ? deg[i] : 0;
    tmp[t] = v;
    __syncthreads();
    for (int off = 1; off < 1024; off <<= 1) {
        int add = (t >= off) ? tmp[t - off] : 0;
        __syncthreads();
        tmp[t] += add;
        __syncthreads();
    }
    if (i < N_NODES) offs[i] = tmp[t] - v;
    if (t == 1023) bsum[b] = tmp[t];
}

// scan3 with fused block-prefix (scan2): first wave reduces bsum[0..b-1]
__global__ __launch_bounds__(1024) void k_scan3(int* __restrict__ offs,
                                                const int* __restrict__ bsum,
                                                int* __restrict__ cursor, int nb) {
    __shared__ int pfx;
    int b = blockIdx.x, t = threadIdx.x;
    if (t < 64) {
        int v = (t < nb && t < b) ? bsum[t] : 0;
        v = wred_sum_i(v);
        if (t == 0) pfx = v;
    }
    __syncthreads();
    int i = b * 1024 + t;
    if (i < N_NODES) {
        int o = offs[i] + pfx;
        offs[i] = o;
        cursor[i] = o;
    }
    if (b == 0 && t == 0) offs[N_NODES] = N_EDGES;
}

__global__ void k_scatter(const int* __restrict__ src, const int* __restrict__ dst,
                          int* __restrict__ cursor, int* __restrict__ csrc) {
    int i = blockIdx.x * 256 + threadIdx.x;
    if (i < N_EDGES) {
        int p = atomicAdd(&cursor[dst[i]], 1);
        csrc[p] = src[i];
    }
}

// ---------------- fused W pre-pack (all 3 layers, one dispatch) ----------------
__device__ __forceinline__ u16 pack_elem(const float* W, int i, int K, int NT, int NOUT) {
    int j = i & 7;
    int lane = (i >> 3) & 63;
    int rest = i >> 9;
    int nt = rest % NT;
    int kt = rest / NT;
    int k = kt * 32 + (lane >> 4) * 8 + j;
    int col = nt * 16 + (lane & 15);
    float v = (col < NOUT) ? W[(size_t)k * NOUT + col] : 0.f;
    return (u16)bf16r(v);
}
__device__ __forceinline__ u16 pack_elem3(const float* W, int i) {
    int j = i & 7;
    int lane = (i >> 3) & 63;
    int rest = i >> 9;
    int nt = rest % 12;
    int kt = rest / 12;
    int k = kt * 32 + (lane >> 4) * 8 + j;
    int col = nt * 16 + (lane & 15);
    int h = col / 48, d = col % 48;
    float v = (d < 47) ? W[(size_t)k * 188 + h * 47 + d] : 0.f;
    return (u16)bf16r(v);
}
__global__ void prep_all(const float* __restrict__ W1, const float* __restrict__ W2,
                         const float* __restrict__ W3, u16* __restrict__ wp1,
                         u16* __restrict__ wp2, u16* __restrict__ wp3) {
    int idx = blockIdx.x * 256 + threadIdx.x;
    if (idx < 32768) {
        wp1[idx] = pack_elem(W1, idx, 256, 8, 128);
    } else if (idx < 49152) {
        int i = idx - 32768;
        wp2[i] = pack_elem(W2, i, 128, 8, 128);
    } else if (idx < 73728) {
        int i = idx - 49152;
        wp3[i] = pack_elem3(W3, i);
    }
}

// ---------------- MFMA GEMM: feat(bf16,[N,NP]) = A @ W (+fused attn dots) ----------------
template <int K, int NOUT, int NP, bool AF32, bool DOTS, bool HEADPAD>
__global__ __launch_bounds__(256) void gemm_mfma(const void* __restrict__ Av,
                                                 const u16* __restrict__ Wp,
                                                 u16* __restrict__ feat,
                                                 const float* __restrict__ al,
                                                 const float* __restrict__ ar,
                                                 float* __restrict__ el,
                                                 float* __restrict__ er) {
    constexpr int NT = NP / 16;
    constexpr int KT = K / 32;
    int w = threadIdx.x >> 6, l = threadIdx.x & 63;
    int tile_m0 = blockIdx.x * 64 + w * 16;
    int c15 = l & 15;
    int rowA = tile_m0 + c15;
    if (rowA >= N_NODES) rowA = N_NODES - 1;
    int g = l >> 4;

    f32x4 acc[NT];
#pragma unroll
    for (int nt = 0; nt < NT; ++nt) acc[nt] = (f32x4){0.f, 0.f, 0.f, 0.f};

    for (int kt = 0; kt < KT; ++kt) {
        bf16x8 a;
        if constexpr (AF32) {
            const float* ap = (const float*)Av + (size_t)rowA * K + kt * 32 + g * 8;
            float4 f0 = *reinterpret_cast<const float4*>(ap);
            float4 f1 = *reinterpret_cast<const float4*>(ap + 4);
            a[0] = bf16r(f0.x); a[1] = bf16r(f0.y); a[2] = bf16r(f0.z); a[3] = bf16r(f0.w);
            a[4] = bf16r(f1.x); a[5] = bf16r(f1.y); a[6] = bf16r(f1.z); a[7] = bf16r(f1.w);
        } else {
            a = *reinterpret_cast<const bf16x8*>((const u16*)Av + (size_t)rowA * K + kt * 32 + g * 8);
        }
        const u16* wp = Wp + ((size_t)kt * NT) * 512 + (size_t)l * 8;
#pragma unroll
        for (int nt = 0; nt < NT; ++nt) {
            bf16x8 b = *reinterpret_cast<const bf16x8*>(wp + nt * 512);
            acc[nt] = __builtin_amdgcn_mfma_f32_16x16x32_bf16(a, b, acc[nt], 0, 0, 0);
        }
    }

    int rowD0 = tile_m0 + g * 4;
#pragma unroll
    for (int nt = 0; nt < NT; ++nt) {
        int col = nt * 16 + c15;
#pragma unroll
        for (int r = 0; r < 4; ++r) {
            int row = rowD0 + r;
            if (row < N_NODES)
                feat[(size_t)row * NP + col] = (u16)bf16r(acc[nt][r]);
        }
    }

    if constexpr (DOTS) {
        float alv[NT], arv[NT];
#pragma unroll
        for (int nt = 0; nt < NT; ++nt) {
            if constexpr (HEADPAD) {
                int h = nt / 3, m = nt % 3;
                if (m == 2) {
                    alv[nt] = (c15 < 15) ? al[h * 47 + 32 + c15] : 0.f;
                    arv[nt] = (c15 < 15) ? ar[h * 47 + 32 + c15] : 0.f;
                } else {
                    alv[nt] = al[h * 47 + m * 16 + c15];
                    arv[nt] = ar[h * 47 + m * 16 + c15];
                }
            } else {
                alv[nt] = al[nt * 16 + c15];
                arv[nt] = ar[nt * 16 + c15];
            }
        }
#pragma unroll
        for (int r = 0; r < 4; ++r) {
            float hlv[NH] = {0.f, 0.f, 0.f, 0.f};
            float hrv[NH] = {0.f, 0.f, 0.f, 0.f};
#pragma unroll
            for (int nt = 0; nt < NT; ++nt) {
                constexpr int NTH = NT / NH;
                int h = nt / NTH;
                hlv[h] = fmaf(acc[nt][r], alv[nt], hlv[h]);
                hrv[h] = fmaf(acc[nt][r], arv[nt], hrv[h]);
            }
#pragma unroll
            for (int o = 1; o < 16; o <<= 1) {
#pragma unroll
                for (int j = 0; j < NH; ++j) {
                    hlv[j] += __shfl_xor(hlv[j], o);
                    hrv[j] += __shfl_xor(hrv[j], o);
                }
            }
            int row = rowD0 + r;
            if (c15 == 0 && row < N_NODES) {
                *reinterpret_cast<float4*>(el + (size_t)row * NH) =
                    make_float4(hlv[0], hlv[1], hlv[2], hlv[3]);
                *reinterpret_cast<float4*>(er + (size_t)row * NH) =
                    make_float4(hrv[0], hrv[1], hrv[2], hrv[3]);
            }
        }
    }
}

// ---------------- per-chunk alpha -> LDS (transposed) + premultiplied row byte offsets ----
__device__ __forceinline__ void alpha_chunk_T(const float* __restrict__ el,
                                              const int* __restrict__ csrc,
                                              float4 erv, int base, int i1, u32 rowb,
                                              float4 mref, float4 vinv, bool online,
                                              float* __restrict__ lalT,
                                              u32* __restrict__ loff, int lane) {
    int e = base + lane;
    bool act = e < i1;
    int srcn = act ? csrc[e] : 0;
    float4 elv = make_float4(0.f, 0.f, 0.f, 0.f);
    if (act) elv = *reinterpret_cast<const float4*>(el + (size_t)srcn * NH);
    float e0 = elv.x + erv.x; e0 = e0 >= 0.f ? e0 : 0.2f * e0;
    float e1 = elv.y + erv.y; e1 = e1 >= 0.f ? e1 : 0.2f * e1;
    float e2 = elv.z + erv.z; e2 = e2 >= 0.f ? e2 : 0.2f * e2;
    float e3 = elv.w + erv.w; e3 = e3 >= 0.f ? e3 : 0.2f * e3;
    float4 a4;
    if (online) {
        const float NEG = -__builtin_inff();
        float f0 = act ? e0 : NEG, f1 = act ? e1 : NEG, f2 = act ? e2 : NEG, f3 = act ? e3 : NEG;
        float m0 = wred_max(f0), m1 = wred_max(f1), m2 = wred_max(f2), m3 = wred_max(f3);
        float p0 = act ? __expf(e0 - m0) : 0.f;
        float p1 = act ? __expf(e1 - m1) : 0.f;
        float p2 = act ? __expf(e2 - m2) : 0.f;
        float p3 = act ? __expf(e3 - m3) : 0.f;
        float s0 = wred_sum(p0), s1 = wred_sum(p1), s2 = wred_sum(p2), s3 = wred_sum(p3);
        a4 = make_float4(act ? p0 / s0 : 0.f, act ? p1 / s1 : 0.f,
                         act ? p2 / s2 : 0.f, act ? p3 / s3 : 0.f);
    } else {
        a4 = make_float4(act ? __expf(e0 - mref.x) * vinv.x : 0.f,
                         act ? __expf(e1 - mref.y) * vinv.y : 0.f,
                         act ? __expf(e2 - mref.z) * vinv.z : 0.f,
                         act ? __expf(e3 - mref.w) * vinv.w : 0.f);
    }
    lalT[0 * LSTR + lane] = a4.x;
    lalT[1 * LSTR + lane] = a4.y;
    lalT[2 * LSTR + lane] = a4.z;
    lalT[3 * LSTR + lane] = a4.w;
    loff[lane] = (u32)srcn * rowb;
}

// global-stats pass for deg>64 nodes
__device__ __forceinline__ void stats_pass(const float* __restrict__ el,
                                           const int* __restrict__ csrc,
                                           float4 erv, int i0, int i1, int lane,
                                           float4& mout, float4& vout) {
    const float NEG = -__builtin_inff();
    float m0 = NEG, m1 = NEG, m2 = NEG, m3 = NEG;
    float s0 = 0.f, s1 = 0.f, s2 = 0.f, s3 = 0.f;
    for (int base = i0; base < i1; base += 64) {
        int i = base + lane;
        bool act = i < i1;
        int srcn = act ? csrc[i] : 0;
        float4 elv = make_float4(0.f, 0.f, 0.f, 0.f);
        if (act) elv = *reinterpret_cast<const float4*>(el + (size_t)srcn * NH);
        float e0 = elv.x + erv.x; e0 = e0 >= 0.f ? e0 : 0.2f * e0;
        float e1 = elv.y + erv.y; e1 = e1 >= 0.f ? e1 : 0.2f * e1;
        float e2 = elv.z + erv.z; e2 = e2 >= 0.f ? e2 : 0.2f * e2;
        float e3 = elv.w + erv.w; e3 = e3 >= 0.f ? e3 : 0.2f * e3;
        if (!act) { e0 = NEG; e1 = NEG; e2 = NEG; e3 = NEG; }
        float c0 = wred_max(e0), c1 = wred_max(e1), c2 = wred_max(e2), c3 = wred_max(e3);
        float nm0 = fmaxf(m0, c0), nm1 = fmaxf(m1, c1), nm2 = fmaxf(m2, c2), nm3 = fmaxf(m3, c3);
        float p0 = act ? __expf(e0 - nm0) : 0.f;
        float p1 = act ? __expf(e1 - nm1) : 0.f;
        float p2 = act ? __expf(e2 - nm2) : 0.f;
        float p3 = act ? __expf(e3 - nm3) : 0.f;
        float S0 = wred_sum(p0), S1 = wred_sum(p1), S2 = wred_sum(p2), S3 = wred_sum(p3);
        s0 = s0 * __expf(m0 - nm0) + S0; m0 = nm0;
        s1 = s1 * __expf(m1 - nm1) + S1; m1 = nm1;
        s2 = s2 * __expf(m2 - nm2) + S2; m2 = nm2;
        s3 = s3 * __expf(m3 - nm3) + S3; m3 = nm3;
    }
    mout = make_float4(m0, m1, m2, m3);
    vout = make_float4(1.f / s0, 1.f / s1, 1.f / s2, 1.f / s3);
}

// ---------------- fused softmax+aggregation, layers 1-2 (128 cols) ----------------
// per-lane 2-col layout (best variant, R13) with premultiplied offsets.
__global__ __launch_bounds__(256) void gat_agg128(const u16* __restrict__ feat,
                                                  const float* __restrict__ el,
                                                  const float* __restrict__ er,
                                                  const int* __restrict__ offs,
                                                  const int* __restrict__ csrc,
                                                  u16* __restrict__ out) {
    __shared__ float lalT[4][4][LSTR];
    __shared__ u32 loff[4][64];
    int wave = threadIdx.x >> 6;
    int lane = threadIdx.x & 63;
    int n = blockIdx.x * 4 + wave;
    int h = lane >> 4;
    u32 lo4 = (u32)lane * 4u;
    int i0 = offs[n], i1 = offs[n + 1];
    int d = i1 - i0;
    f32x2 acc = (f32x2){0.f, 0.f};
    if (d > 0) {
        float4 erv = *reinterpret_cast<const float4*>(er + (size_t)n * NH);
        float4 mref = make_float4(0.f, 0.f, 0.f, 0.f), vinv = mref;
        bool onechunk = d <= 64;
        if (!onechunk) stats_pass(el, csrc, erv, i0, i1, lane, mref, vinv);
        const char* fbase = (const char*)feat;
        for (int base = i0; base < i1; base += 64) {
            alpha_chunk_T(el, csrc, erv, base, i1, 256u, mref, vinv, onechunk,
                          &lalT[wave][0][0], &loff[wave][0], lane);
            int cnt = i1 - base; if (cnt > 64) cnt = 64;
            int cpad = (cnt + 3) & ~3;
            for (int j = 0; j < cpad; j += 4) {
                uint4 ov = *reinterpret_cast<const uint4*>(&loff[wave][j]);
                float4 aq = *reinterpret_cast<const float4*>(&lalT[wave][h][j]);
                f32x2 aqLo = (f32x2){aq.x, aq.y};
                f32x2 aqHi = (f32x2){aq.z, aq.w};
                u32 q0 = *reinterpret_cast<const u32*>(fbase + (ov.x + lo4));
                u32 q1 = *reinterpret_cast<const u32*>(fbase + (ov.y + lo4));
                u32 q2 = *reinterpret_cast<const u32*>(fbase + (ov.z + lo4));
                u32 q3 = *reinterpret_cast<const u32*>(fbase + (ov.w + lo4));
                pkfma_lo(acc, aqLo, bf2_to_v2(q0));
                pkfma_hi(acc, aqLo, bf2_to_v2(q1));
                pkfma_lo(acc, aqHi, bf2_to_v2(q2));
                pkfma_hi(acc, aqHi, bf2_to_v2(q3));
            }
        }
    }
    float ox = acc.x > 0.f ? acc.x : expm1f(acc.x);
    float oy = acc.y > 0.f ? acc.y : expm1f(acc.y);
    *reinterpret_cast<u32*>(out + (size_t)n * 128 + 2 * lane) = pack_bf2(ox, oy);
}

// ---------------- fused softmax+aggregation, layer 3 (192-col head-major-48) ----------------
// slice-cooperative (best variant, R14): 24-of-32 lanes x dwordx4 = one 384B row.
__global__ __launch_bounds__(256) void gat_agg_final(const u16* __restrict__ feat,
                                                     const float* __restrict__ el,
                                                     const float* __restrict__ er,
                                                     const int* __restrict__ offs,
                                                     const int* __restrict__ csrc,
                                                     float* __restrict__ out) {
    __shared__ float lalT[4][4][LSTR];
    __shared__ u32 loff[4][64];
    __shared__ float lds[4][192];
    int wave = threadIdx.x >> 6;
    int lane = threadIdx.x & 63;
    int n = blockIdx.x * 4 + wave;
    int sub = lane >> 5, sl = lane & 31;
    bool act = sl < 24;
    int h = act ? (sl / 6) : 0;      // 6 slices per 48-col head
    u32 soff = (u32)sl * 16u;
    int i0 = offs[n], i1 = offs[n + 1];
    int d = i1 - i0;
    f32x2 acc0 = (f32x2){0.f, 0.f}, acc1 = acc0, acc2 = acc0, acc3 = acc0;
    if (d > 0) {
        float4 erv = *reinterpret_cast<const float4*>(er + (size_t)n * NH);
        float4 mref = make_float4(0.f, 0.f, 0.f, 0.f), vinv = mref;
        bool onechunk = d <= 64;
        if (!onechunk) stats_pass(el, csrc, erv, i0, i1, lane, mref, vinv);
        const char* fbase = (const char*)feat;
        for (int base = i0; base < i1; base += 64) {
            alpha_chunk_T(el, csrc, erv, base, i1, 384u, mref, vinv, onechunk,
                          &lalT[wave][0][0], &loff[wave][0], lane);
            int cnt = i1 - base; if (cnt > 64) cnt = 64;
            int cpad = (cnt + 3) & ~3;
            if (act) {
                for (int j = 0; j < cpad; j += 4) {
                    u32 o0 = loff[wave][j + sub] + soff;
                    u32 o1 = loff[wave][j + 2 + sub] + soff;
                    uint4 q0 = *reinterpret_cast<const uint4*>(fbase + o0);
                    uint4 q1 = *reinterpret_cast<const uint4*>(fbase + o1);
                    f32x2 ap = (f32x2){lalT[wave][h][j + sub], lalT[wave][h][j + 2 + sub]};
                    pkfma_lo(acc0, ap, bf2_to_v2(q0.x));
                    pkfma_lo(acc1, ap, bf2_to_v2(q0.y));
                    pkfma_lo(acc2, ap, bf2_to_v2(q0.z));
                    pkfma_lo(acc3, ap, bf2_to_v2(q0.w));
                    pkfma_hi(acc0, ap, bf2_to_v2(q1.x));
                    pkfma_hi(acc1, ap, bf2_to_v2(q1.y));
                    pkfma_hi(acc2, ap, bf2_to_v2(q1.z));
                    pkfma_hi(acc3, ap, bf2_to_v2(q1.w));
                }
            }
        }
    }
    float v[8] = {acc0.x, acc0.y, acc1.x, acc1.y, acc2.x, acc2.y, acc3.x, acc3.y};
#pragma unroll
    for (int k = 0; k < 8; ++k) v[k] += __shfl_xor(v[k], 32);
    if (sub == 0 && act) {
        float4 lo = make_float4(v[0], v[1], v[2], v[3]);
        float4 hi = make_float4(v[4], v[5], v[6], v[7]);
        *reinterpret_cast<float4*>(&lds[wave][sl * 8]) = lo;
        *reinterpret_cast<float4*>(&lds[wave][sl * 8 + 4]) = hi;
    }
    __syncthreads();
    float u = (lane < 47)
                  ? 0.25f * (lds[wave][lane] + lds[wave][48 + lane] +
                             lds[wave][96 + lane] + lds[wave][144 + lane])
                  : -__builtin_inff();
    float mx = u;
#pragma unroll
    for (int o = 32; o > 0; o >>= 1) mx = fmaxf(mx, __shfl_xor(mx, o));
    float ex = (lane < 47) ? __expf(u - mx) : 0.f;
    float sm = ex;
#pragma unroll
    for (int o = 32; o > 0; o >>= 1) sm += __shfl_xor(sm, o);
    if (lane < 47) out[(size_t)n * 47 + lane] = u - mx - logf(sm);
}

// ---------------- launch ----------------

extern "C" void kernel_launch(void* const* d_in, const int* in_sizes, int n_in,
                              void* d_out, int out_size, void* d_ws, size_t ws_size,
                              hipStream_t stream) {
    const float* x = (const float*)d_in[0];
    const int* src = (const int*)d_in[1];
    const int* dst = (const int*)d_in[2];
    const float* W1 = (const float*)d_in[3];
    const float* al1 = (const float*)d_in[4];
    const float* ar1 = (const float*)d_in[5];
    const float* W2 = (const float*)d_in[6];
    const float* al2 = (const float*)d_in[7];
    const float* ar2 = (const float*)d_in[8];
    const float* W3 = (const float*)d_in[9];
    const float* al3 = (const float*)d_in[10];
    const float* ar3 = (const float*)d_in[11];
    float* out = (float*)d_out;

    char* p = (char*)d_ws;
    auto alloc = [&](size_t bytes) {
        char* r = p;
        p += (bytes + 255) & ~(size_t)255;
        return r;
    };
    u16* bufA = (u16*)alloc((size_t)N_NODES * 128 * 2);
    u16* bufC = (u16*)alloc((size_t)N_NODES * 128 * 2);
    u16* featb = (u16*)alloc((size_t)N_NODES * 192 * 2);
    float* el = (float*)alloc((size_t)N_NODES * NH * 4);
    float* er = (float*)alloc((size_t)N_NODES * NH * 4);
    u16* wp1 = (u16*)alloc((size_t)32768 * 2);
    u16* wp2 = (u16*)alloc((size_t)16384 * 2);
    u16* wp3 = (u16*)alloc((size_t)24576 * 2);
    int* deg = (int*)alloc((size_t)N_NODES * 4);
    int* offs = (int*)alloc((size_t)(N_NODES + 1) * 4);
    int* cursor = (int*)alloc((size_t)N_NODES * 4);
    int* bsum = (int*)alloc(64 * 4);
    int* csrc = (int*)alloc((size_t)N_EDGES * 4);

    // fused W pre-pack (one dispatch)
    prep_all<<<288, 256, 0, stream>>>(W1, W2, W3, wp1, wp2, wp3);

    // CSR by dst (scan2 fused into scan3)
    hipMemsetAsync(deg, 0, (size_t)N_NODES * 4, stream);
    k_hist<<<(N_EDGES + 255) / 256, 256, 0, stream>>>(dst, deg);
    k_scan1<<<49, 1024, 0, stream>>>(deg, offs, bsum);
    k_scan3<<<49, 1024, 0, stream>>>(offs, bsum, cursor, 49);
    k_scatter<<<(N_EDGES + 255) / 256, 256, 0, stream>>>(src, dst, cursor, csrc);

    int gemm_grid = (N_NODES + 63) / 64;
    // layer 1
    gemm_mfma<256, 128, 128, true, true, false><<<gemm_grid, 256, 0, stream>>>(x, wp1, featb, al1, ar1, el, er);
    gat_agg128<<<N_NODES / 4, 256, 0, stream>>>(featb, el, er, offs, csrc, bufA);
    // layer 2
    gemm_mfma<128, 128, 128, false, true, false><<<gemm_grid, 256, 0, stream>>>(bufA, wp2, featb, al2, ar2, el, er);
    gat_agg128<<<N_NODES / 4, 256, 0, stream>>>(featb, el, er, offs, csrc, bufC);
    // layer 3 (head-major-48 padded layout; dots fused)
    gemm_mfma<128, 192, 192, false, true, true><<<gemm_grid, 256, 0, stream>>>(bufC, wp3, featb, al3, ar3, el, er);
    gat_agg_final<<<N_NODES / 4, 256, 0, stream>>>(featb, el, er, offs, csrc, out);
}

// Round 16
// 285.285 us; speedup vs baseline: 1.0457x; 1.0329x over previous
//
#include <hip/hip_runtime.h>
#include <hip/hip_bf16.h>
#include <math.h>
#include <string.h>

#define N_NODES 50000
#define N_EDGES 800000
#define NH 4
#define LSTR 68   // padded lalT stride (floats): head rows 272B apart -> conflict-free

typedef unsigned int u32;
typedef unsigned short u16;
typedef __attribute__((ext_vector_type(8))) short bf16x8;
typedef __attribute__((ext_vector_type(4))) float f32x4;
typedef __attribute__((ext_vector_type(2))) float f32x2;

__device__ __forceinline__ u32 pack_bf2(float a, float b) {
    __hip_bfloat162 h2 = __float22bfloat162_rn(make_float2(a, b));
    u32 r;
    memcpy(&r, &h2, 4);
    return r;
}
__device__ __forceinline__ f32x2 bf2_to_v2(u32 u) {
    f32x2 v;
    v.x = __uint_as_float(u << 16);
    v.y = __uint_as_float(u & 0xffff0000u);
    return v;
}
__device__ __forceinline__ short bf16r(float f) {
    __hip_bfloat16 h = __float2bfloat16(f);
    short s;
    memcpy(&s, &h, 2);
    return s;
}
// acc += broadcast(a.lo) * b   (VOP3P op_sel broadcast of src0 low register)
__device__ __forceinline__ void pkfma_lo(f32x2& acc, f32x2 a, f32x2 b) {
    asm("v_pk_fma_f32 %0, %1, %2, %0 op_sel:[0,0,0] op_sel_hi:[0,1,1]"
        : "+v"(acc) : "v"(a), "v"(b));
}
// acc += broadcast(a.hi) * b
__device__ __forceinline__ void pkfma_hi(f32x2& acc, f32x2 a, f32x2 b) {
    asm("v_pk_fma_f32 %0, %1, %2, %0 op_sel:[1,0,0] op_sel_hi:[1,1,1]"
        : "+v"(acc) : "v"(a), "v"(b));
}

__device__ __forceinline__ float wred_max(float v) {
#pragma unroll
    for (int o = 32; o > 0; o >>= 1) v = fmaxf(v, __shfl_xor(v, o));
    return v;
}
__device__ __forceinline__ float wred_sum(float v) {
#pragma unroll
    for (int o = 32; o > 0; o >>= 1) v += __shfl_xor(v, o);
    return v;
}
__device__ __forceinline__ int wred_sum_i(int v) {
#pragma unroll
    for (int o = 32; o > 0; o >>= 1) v += __shfl_xor(v, o);
    return v;
}

// ---------------- CSR build ----------------

__global__ void k_hist(const int* __restrict__ dst, int* __restrict__ deg) {
    int i = blockIdx.x * 256 + threadIdx.x;
    if (i < N_EDGES) atomicAdd(&deg[dst[i]], 1);
}

__global__ __launch_bounds__(1024) void k_scan1(const int* __restrict__ deg,
                                                int* __restrict__ offs,
                                                int* __restrict__ bsum) {
    __shared__ int tmp[1024];
    int b = blockIdx.x, t = threadIdx.x;
    int i = b * 1024 + t;
    int v = (i < N_NODES) ? deg[i] : 0;
    tmp[t] = v;
    __syncthreads();
    for (int off = 1; off < 1024; off <<= 1) {
        int add = (t >= off) ? tmp[t - off] : 0;
        __syncthreads();
        tmp[t] += add;
        __syncthreads();
    }
    if (i < N_NODES) offs[i] = tmp[t] - v;
    if (t == 1023) bsum[b] = tmp[t];
}

// scan3 with fused block-prefix (scan2): first wave reduces bsum[0..b-1]
__global__ __launch_bounds__(1024) void k_scan3(int* __restrict__ offs,
                                                const int* __restrict__ bsum,
                                                int* __restrict__ cursor, int nb) {
    __shared__ int pfx;
    int b = blockIdx.x, t = threadIdx.x;
    if (t < 64) {
        int v = (t < nb && t < b) ? bsum[t] : 0;
        v = wred_sum_i(v);
        if (t == 0) pfx = v;
    }
    __syncthreads();
    int i = b * 1024 + t;
    if (i < N_NODES) {
        int o = offs[i] + pfx;
        offs[i] = o;
        cursor[i] = o;
    }
    if (b == 0 && t == 0) offs[N_NODES] = N_EDGES;
}

__global__ void k_scatter(const int* __restrict__ src, const int* __restrict__ dst,
                          int* __restrict__ cursor, int* __restrict__ csrc) {
    int i = blockIdx.x * 256 + threadIdx.x;
    if (i < N_EDGES) {
        int p = atomicAdd(&cursor[dst[i]], 1);
        csrc[p] = src[i];
    }
}

// ---------------- fused W pre-pack (all 3 layers, one dispatch) ----------------
__device__ __forceinline__ u16 pack_elem(const float* W, int i, int K, int NT, int NOUT) {
    int j = i & 7;
    int lane = (i >> 3) & 63;
    int rest = i >> 9;
    int nt = rest % NT;
    int kt = rest / NT;
    int k = kt * 32 + (lane >> 4) * 8 + j;
    int col = nt * 16 + (lane & 15);
    float v = (col < NOUT) ? W[(size_t)k * NOUT + col] : 0.f;
    return (u16)bf16r(v);
}
__device__ __forceinline__ u16 pack_elem3(const float* W, int i) {
    int j = i & 7;
    int lane = (i >> 3) & 63;
    int rest = i >> 9;
    int nt = rest % 12;
    int kt = rest / 12;
    int k = kt * 32 + (lane >> 4) * 8 + j;
    int col = nt * 16 + (lane & 15);
    int h = col / 48, d = col % 48;
    float v = (d < 47) ? W[(size_t)k * 188 + h * 47 + d] : 0.f;
    return (u16)bf16r(v);
}
__global__ void prep_all(const float* __restrict__ W1, const float* __restrict__ W2,
                         const float* __restrict__ W3, u16* __restrict__ wp1,
                         u16* __restrict__ wp2, u16* __restrict__ wp3) {
    int idx = blockIdx.x * 256 + threadIdx.x;
    if (idx < 32768) {
        wp1[idx] = pack_elem(W1, idx, 256, 8, 128);
    } else if (idx < 49152) {
        int i = idx - 32768;
        wp2[i] = pack_elem(W2, i, 128, 8, 128);
    } else if (idx < 73728) {
        int i = idx - 49152;
        wp3[i] = pack_elem3(W3, i);
    }
}

// ---------------- MFMA GEMM: feat(bf16,[N,NP]) = A @ W (+fused attn dots) ----------------
template <int K, int NOUT, int NP, bool AF32, bool DOTS, bool HEADPAD>
__global__ __launch_bounds__(256) void gemm_mfma(const void* __restrict__ Av,
                                                 const u16* __restrict__ Wp,
                                                 u16* __restrict__ feat,
                                                 const float* __restrict__ al,
                                                 const float* __restrict__ ar,
                                                 float* __restrict__ el,
                                                 float* __restrict__ er) {
    constexpr int NT = NP / 16;
    constexpr int KT = K / 32;
    int w = threadIdx.x >> 6, l = threadIdx.x & 63;
    int tile_m0 = blockIdx.x * 64 + w * 16;
    int c15 = l & 15;
    int rowA = tile_m0 + c15;
    if (rowA >= N_NODES) rowA = N_NODES - 1;
    int g = l >> 4;

    f32x4 acc[NT];
#pragma unroll
    for (int nt = 0; nt < NT; ++nt) acc[nt] = (f32x4){0.f, 0.f, 0.f, 0.f};

    for (int kt = 0; kt < KT; ++kt) {
        bf16x8 a;
        if constexpr (AF32) {
            const float* ap = (const float*)Av + (size_t)rowA * K + kt * 32 + g * 8;
            float4 f0 = *reinterpret_cast<const float4*>(ap);
            float4 f1 = *reinterpret_cast<const float4*>(ap + 4);
            a[0] = bf16r(f0.x); a[1] = bf16r(f0.y); a[2] = bf16r(f0.z); a[3] = bf16r(f0.w);
            a[4] = bf16r(f1.x); a[5] = bf16r(f1.y); a[6] = bf16r(f1.z); a[7] = bf16r(f1.w);
        } else {
            a = *reinterpret_cast<const bf16x8*>((const u16*)Av + (size_t)rowA * K + kt * 32 + g * 8);
        }
        const u16* wp = Wp + ((size_t)kt * NT) * 512 + (size_t)l * 8;
#pragma unroll
        for (int nt = 0; nt < NT; ++nt) {
            bf16x8 b = *reinterpret_cast<const bf16x8*>(wp + nt * 512);
            acc[nt] = __builtin_amdgcn_mfma_f32_16x16x32_bf16(a, b, acc[nt], 0, 0, 0);
        }
    }

    int rowD0 = tile_m0 + g * 4;
#pragma unroll
    for (int nt = 0; nt < NT; ++nt) {
        int col = nt * 16 + c15;
#pragma unroll
        for (int r = 0; r < 4; ++r) {
            int row = rowD0 + r;
            if (row < N_NODES)
                feat[(size_t)row * NP + col] = (u16)bf16r(acc[nt][r]);
        }
    }

    if constexpr (DOTS) {
        float alv[NT], arv[NT];
#pragma unroll
        for (int nt = 0; nt < NT; ++nt) {
            if constexpr (HEADPAD) {
                int h = nt / 3, m = nt % 3;
                if (m == 2) {
                    alv[nt] = (c15 < 15) ? al[h * 47 + 32 + c15] : 0.f;
                    arv[nt] = (c15 < 15) ? ar[h * 47 + 32 + c15] : 0.f;
                } else {
                    alv[nt] = al[h * 47 + m * 16 + c15];
                    arv[nt] = ar[h * 47 + m * 16 + c15];
                }
            } else {
                alv[nt] = al[nt * 16 + c15];
                arv[nt] = ar[nt * 16 + c15];
            }
        }
#pragma unroll
        for (int r = 0; r < 4; ++r) {
            float hlv[NH] = {0.f, 0.f, 0.f, 0.f};
            float hrv[NH] = {0.f, 0.f, 0.f, 0.f};
#pragma unroll
            for (int nt = 0; nt < NT; ++nt) {
                constexpr int NTH = NT / NH;
                int h = nt / NTH;
                hlv[h] = fmaf(acc[nt][r], alv[nt], hlv[h]);
                hrv[h] = fmaf(acc[nt][r], arv[nt], hrv[h]);
            }
#pragma unroll
            for (int o = 1; o < 16; o <<= 1) {
#pragma unroll
                for (int j = 0; j < NH; ++j) {
                    hlv[j] += __shfl_xor(hlv[j], o);
                    hrv[j] += __shfl_xor(hrv[j], o);
                }
            }
            int row = rowD0 + r;
            if (c15 == 0 && row < N_NODES) {
                *reinterpret_cast<float4*>(el + (size_t)row * NH) =
                    make_float4(hlv[0], hlv[1], hlv[2], hlv[3]);
                *reinterpret_cast<float4*>(er + (size_t)row * NH) =
                    make_float4(hrv[0], hrv[1], hrv[2], hrv[3]);
            }
        }
    }
}

// ---------------- FAST alpha for deg<=64: (edge,head)-parallel, group-16 reduces ----------
// lane = h*16 + e; processes ceil(cnt/16) passes; writes alpha to lalT[h][edge], row byte
// offsets (premultiplied) to loff[edge]. Pad slots stay {alpha=0, off=0} (gather-safe).
__device__ __forceinline__ void alpha_fast(const float* __restrict__ el,
                                           const float* __restrict__ er_n,
                                           const int* __restrict__ csrc,
                                           int i0, int cnt, u32 rowb,
                                           float* __restrict__ lalT,
                                           u32* __restrict__ loff, int lane) {
    const float NEG = -__builtin_inff();
    int h = lane >> 4, e15 = lane & 15;
    float erh = er_n[h];
    // prefill pad-safe defaults
    lalT[0 * LSTR + lane] = 0.f;
    lalT[1 * LSTR + lane] = 0.f;
    lalT[2 * LSTR + lane] = 0.f;
    lalT[3 * LSTR + lane] = 0.f;
    loff[lane] = 0u;
    int npass = (cnt + 15) >> 4;
    float m = NEG, s = 0.f;
#pragma unroll
    for (int p = 0; p < 4; ++p) {
        if (p < npass) {
            int idx = (p << 4) + e15;
            bool act = idx < cnt;
            int srcn = act ? csrc[i0 + idx] : 0;
            float ev = act ? el[(size_t)srcn * NH + h] + erh : NEG;
            ev = ev >= 0.f ? ev : 0.2f * ev;
            if (act && h == 0) loff[idx] = (u32)srcn * rowb;
            if (act) lalT[h * LSTR + idx] = ev;          // raw energy
            float cm = ev;
            cm = fmaxf(cm, __shfl_xor(cm, 1));
            cm = fmaxf(cm, __shfl_xor(cm, 2));
            cm = fmaxf(cm, __shfl_xor(cm, 4));
            cm = fmaxf(cm, __shfl_xor(cm, 8));
            float nm = fmaxf(m, cm);
            float pv = act ? __expf(ev - nm) : 0.f;
            pv += __shfl_xor(pv, 1);
            pv += __shfl_xor(pv, 2);
            pv += __shfl_xor(pv, 4);
            pv += __shfl_xor(pv, 8);
            s = s * __expf(m - nm) + pv;
            m = nm;
        }
    }
    float vinv = 1.f / s;
#pragma unroll
    for (int p = 0; p < 4; ++p) {
        if (p < npass) {
            int idx = (p << 4) + e15;
            if (idx < cnt) {
                float val = lalT[h * LSTR + idx];
                lalT[h * LSTR + idx] = __expf(val - m) * vinv;
            }
        }
    }
}

// ---------------- slow-path alpha (deg>64, rare): per-edge lanes, precomputed stats ----
__device__ __forceinline__ void alpha_chunk_T(const float* __restrict__ el,
                                              const int* __restrict__ csrc,
                                              float4 erv, int base, int i1, u32 rowb,
                                              float4 mref, float4 vinv,
                                              float* __restrict__ lalT,
                                              u32* __restrict__ loff, int lane) {
    int e = base + lane;
    bool act = e < i1;
    int srcn = act ? csrc[e] : 0;
    float4 elv = make_float4(0.f, 0.f, 0.f, 0.f);
    if (act) elv = *reinterpret_cast<const float4*>(el + (size_t)srcn * NH);
    float e0 = elv.x + erv.x; e0 = e0 >= 0.f ? e0 : 0.2f * e0;
    float e1 = elv.y + erv.y; e1 = e1 >= 0.f ? e1 : 0.2f * e1;
    float e2 = elv.z + erv.z; e2 = e2 >= 0.f ? e2 : 0.2f * e2;
    float e3 = elv.w + erv.w; e3 = e3 >= 0.f ? e3 : 0.2f * e3;
    float4 a4 = make_float4(act ? __expf(e0 - mref.x) * vinv.x : 0.f,
                            act ? __expf(e1 - mref.y) * vinv.y : 0.f,
                            act ? __expf(e2 - mref.z) * vinv.z : 0.f,
                            act ? __expf(e3 - mref.w) * vinv.w : 0.f);
    lalT[0 * LSTR + lane] = a4.x;
    lalT[1 * LSTR + lane] = a4.y;
    lalT[2 * LSTR + lane] = a4.z;
    lalT[3 * LSTR + lane] = a4.w;
    loff[lane] = (u32)srcn * rowb;
}

// global-stats pass for deg>64 nodes
__device__ __forceinline__ void stats_pass(const float* __restrict__ el,
                                           const int* __restrict__ csrc,
                                           float4 erv, int i0, int i1, int lane,
                                           float4& mout, float4& vout) {
    const float NEG = -__builtin_inff();
    float m0 = NEG, m1 = NEG, m2 = NEG, m3 = NEG;
    float s0 = 0.f, s1 = 0.f, s2 = 0.f, s3 = 0.f;
    for (int base = i0; base < i1; base += 64) {
        int i = base + lane;
        bool act = i < i1;
        int srcn = act ? csrc[i] : 0;
        float4 elv = make_float4(0.f, 0.f, 0.f, 0.f);
        if (act) elv = *reinterpret_cast<const float4*>(el + (size_t)srcn * NH);
        float e0 = elv.x + erv.x; e0 = e0 >= 0.f ? e0 : 0.2f * e0;
        float e1 = elv.y + erv.y; e1 = e1 >= 0.f ? e1 : 0.2f * e1;
        float e2 = elv.z + erv.z; e2 = e2 >= 0.f ? e2 : 0.2f * e2;
        float e3 = elv.w + erv.w; e3 = e3 >= 0.f ? e3 : 0.2f * e3;
        if (!act) { e0 = NEG; e1 = NEG; e2 = NEG; e3 = NEG; }
        float c0 = wred_max(e0), c1 = wred_max(e1), c2 = wred_max(e2), c3 = wred_max(e3);
        float nm0 = fmaxf(m0, c0), nm1 = fmaxf(m1, c1), nm2 = fmaxf(m2, c2), nm3 = fmaxf(m3, c3);
        float p0 = act ? __expf(e0 - nm0) : 0.f;
        float p1 = act ? __expf(e1 - nm1) : 0.f;
        float p2 = act ? __expf(e2 - nm2) : 0.f;
        float p3 = act ? __expf(e3 - nm3) : 0.f;
        float S0 = wred_sum(p0), S1 = wred_sum(p1), S2 = wred_sum(p2), S3 = wred_sum(p3);
        s0 = s0 * __expf(m0 - nm0) + S0; m0 = nm0;
        s1 = s1 * __expf(m1 - nm1) + S1; m1 = nm1;
        s2 = s2 * __expf(m2 - nm2) + S2; m2 = nm2;
        s3 = s3 * __expf(m3 - nm3) + S3; m3 = nm3;
    }
    mout = make_float4(m0, m1, m2, m3);
    vout = make_float4(1.f / s0, 1.f / s1, 1.f / s2, 1.f / s3);
}

// ---------------- fused softmax+aggregation, layers 1-2 (128 cols) ----------------
__global__ __launch_bounds__(256) void gat_agg128(const u16* __restrict__ feat,
                                                  const float* __restrict__ el,
                                                  const float* __restrict__ er,
                                                  const int* __restrict__ offs,
                                                  const int* __restrict__ csrc,
                                                  u16* __restrict__ out) {
    __shared__ float lalT[4][4][LSTR];
    __shared__ u32 loff[4][64];
    int wave = threadIdx.x >> 6;
    int lane = threadIdx.x & 63;
    int n = blockIdx.x * 4 + wave;
    int h = lane >> 4;
    u32 lo4 = (u32)lane * 4u;
    int i0 = offs[n], i1 = offs[n + 1];
    int d = i1 - i0;
    f32x2 acc = (f32x2){0.f, 0.f};
    const char* fbase = (const char*)feat;
    if (d > 0 && d <= 64) {
        alpha_fast(el, er + (size_t)n * NH, csrc, i0, d, 256u,
                   &lalT[wave][0][0], &loff[wave][0], lane);
        int cpad = (d + 3) & ~3;
        for (int j = 0; j < cpad; j += 4) {
            uint4 ov = *reinterpret_cast<const uint4*>(&loff[wave][j]);
            float4 aq = *reinterpret_cast<const float4*>(&lalT[wave][h][j]);
            f32x2 aqLo = (f32x2){aq.x, aq.y};
            f32x2 aqHi = (f32x2){aq.z, aq.w};
            u32 q0 = *reinterpret_cast<const u32*>(fbase + (ov.x + lo4));
            u32 q1 = *reinterpret_cast<const u32*>(fbase + (ov.y + lo4));
            u32 q2 = *reinterpret_cast<const u32*>(fbase + (ov.z + lo4));
            u32 q3 = *reinterpret_cast<const u32*>(fbase + (ov.w + lo4));
            pkfma_lo(acc, aqLo, bf2_to_v2(q0));
            pkfma_hi(acc, aqLo, bf2_to_v2(q1));
            pkfma_lo(acc, aqHi, bf2_to_v2(q2));
            pkfma_hi(acc, aqHi, bf2_to_v2(q3));
        }
    } else if (d > 64) {
        float4 erv = *reinterpret_cast<const float4*>(er + (size_t)n * NH);
        float4 mref, vinv;
        stats_pass(el, csrc, erv, i0, i1, lane, mref, vinv);
        for (int base = i0; base < i1; base += 64) {
            alpha_chunk_T(el, csrc, erv, base, i1, 256u, mref, vinv,
                          &lalT[wave][0][0], &loff[wave][0], lane);
            int cnt = i1 - base; if (cnt > 64) cnt = 64;
            int cpad = (cnt + 3) & ~3;
            for (int j = 0; j < cpad; j += 4) {
                uint4 ov = *reinterpret_cast<const uint4*>(&loff[wave][j]);
                float4 aq = *reinterpret_cast<const float4*>(&lalT[wave][h][j]);
                f32x2 aqLo = (f32x2){aq.x, aq.y};
                f32x2 aqHi = (f32x2){aq.z, aq.w};
                u32 q0 = *reinterpret_cast<const u32*>(fbase + (ov.x + lo4));
                u32 q1 = *reinterpret_cast<const u32*>(fbase + (ov.y + lo4));
                u32 q2 = *reinterpret_cast<const u32*>(fbase + (ov.z + lo4));
                u32 q3 = *reinterpret_cast<const u32*>(fbase + (ov.w + lo4));
                pkfma_lo(acc, aqLo, bf2_to_v2(q0));
                pkfma_hi(acc, aqLo, bf2_to_v2(q1));
                pkfma_lo(acc, aqHi, bf2_to_v2(q2));
                pkfma_hi(acc, aqHi, bf2_to_v2(q3));
            }
        }
    }
    float ox = acc.x > 0.f ? acc.x : expm1f(acc.x);
    float oy = acc.y > 0.f ? acc.y : expm1f(acc.y);
    *reinterpret_cast<u32*>(out + (size_t)n * 128 + 2 * lane) = pack_bf2(ox, oy);
}

// ---------------- fused softmax+aggregation, layer 3 (192-col head-major-48) ----------------
// slice-cooperative: 24-of-32 lanes x dwordx4 = one 384B row; 2 edges per VMEM instr.
__global__ __launch_bounds__(256) void gat_agg_final(const u16* __restrict__ feat,
                                                     const float* __restrict__ el,
                                                     const float* __restrict__ er,
                                                     const int* __restrict__ offs,
                                                     const int* __restrict__ csrc,
                                                     float* __restrict__ out) {
    __shared__ float lalT[4][4][LSTR];
    __shared__ u32 loff[4][64];
    __shared__ float lds[4][192];
    int wave = threadIdx.x >> 6;
    int lane = threadIdx.x & 63;
    int n = blockIdx.x * 4 + wave;
    int sub = lane >> 5, sl = lane & 31;
    bool act = sl < 24;
    int h = act ? (sl / 6) : 0;      // 6 slices per 48-col head
    u32 soff = (u32)sl * 16u;
    int i0 = offs[n], i1 = offs[n + 1];
    int d = i1 - i0;
    f32x2 acc0 = (f32x2){0.f, 0.f}, acc1 = acc0, acc2 = acc0, acc3 = acc0;
    const char* fbase = (const char*)feat;
    if (d > 0 && d <= 64) {
        alpha_fast(el, er + (size_t)n * NH, csrc, i0, d, 384u,
                   &lalT[wave][0][0], &loff[wave][0], lane);
        int cpad = (d + 3) & ~3;
        if (act) {
            for (int j = 0; j < cpad; j += 4) {
                u32 o0 = loff[wave][j + sub] + soff;
                u32 o1 = loff[wave][j + 2 + sub] + soff;
                uint4 q0 = *reinterpret_cast<const uint4*>(fbase + o0);
                uint4 q1 = *reinterpret_cast<const uint4*>(fbase + o1);
                f32x2 ap = (f32x2){lalT[wave][h][j + sub], lalT[wave][h][j + 2 + sub]};
                pkfma_lo(acc0, ap, bf2_to_v2(q0.x));
                pkfma_lo(acc1, ap, bf2_to_v2(q0.y));
                pkfma_lo(acc2, ap, bf2_to_v2(q0.z));
                pkfma_lo(acc3, ap, bf2_to_v2(q0.w));
                pkfma_hi(acc0, ap, bf2_to_v2(q1.x));
                pkfma_hi(acc1, ap, bf2_to_v2(q1.y));
                pkfma_hi(acc2, ap, bf2_to_v2(q1.z));
                pkfma_hi(acc3, ap, bf2_to_v2(q1.w));
            }
        }
    } else if (d > 64) {
        float4 erv = *reinterpret_cast<const float4*>(er + (size_t)n * NH);
        float4 mref, vinv;
        stats_pass(el, csrc, erv, i0, i1, lane, mref, vinv);
        for (int base = i0; base < i1; base += 64) {
            alpha_chunk_T(el, csrc, erv, base, i1, 384u, mref, vinv,
                          &lalT[wave][0][0], &loff[wave][0], lane);
            int cnt = i1 - base; if (cnt > 64) cnt = 64;
            int cpad = (cnt + 3) & ~3;
            if (act) {
                for (int j = 0; j < cpad; j += 4) {
                    u32 o0 = loff[wave][j + sub] + soff;
                    u32 o1 = loff[wave][j + 2 + sub] + soff;
                    uint4 q0 = *reinterpret_cast<const uint4*>(fbase + o0);
                    uint4 q1 = *reinterpret_cast<const uint4*>(fbase + o1);
                    f32x2 ap = (f32x2){lalT[wave][h][j + sub], lalT[wave][h][j + 2 + sub]};
                    pkfma_lo(acc0, ap, bf2_to_v2(q0.x));
                    pkfma_lo(acc1, ap, bf2_to_v2(q0.y));
                    pkfma_lo(acc2, ap, bf2_to_v2(q0.z));
                    pkfma_lo(acc3, ap, bf2_to_v2(q0.w));
                    pkfma_hi(acc0, ap, bf2_to_v2(q1.x));
                    pkfma_hi(acc1, ap, bf2_to_v2(q1.y));
                    pkfma_hi(acc2, ap, bf2_to_v2(q1.z));
                    pkfma_hi(acc3, ap, bf2_to_v2(q1.w));
                }
            }
        }
    }
    float v[8] = {acc0.x, acc0.y, acc1.x, acc1.y, acc2.x, acc2.y, acc3.x, acc3.y};
#pragma unroll
    for (int k = 0; k < 8; ++k) v[k] += __shfl_xor(v[k], 32);
    if (sub == 0 && act) {
        float4 lo = make_float4(v[0], v[1], v[2], v[3]);
        float4 hi = make_float4(v[4], v[5], v[6], v[7]);
        *reinterpret_cast<float4*>(&lds[wave][sl * 8]) = lo;
        *reinterpret_cast<float4*>(&lds[wave][sl * 8 + 4]) = hi;
    }
    __syncthreads();
    float u = (lane < 47)
                  ? 0.25f * (lds[wave][lane] + lds[wave][48 + lane] +
                             lds[wave][96 + lane] + lds[wave][144 + lane])
                  : -__builtin_inff();
    float mx = u;
#pragma unroll
    for (int o = 32; o > 0; o >>= 1) mx = fmaxf(mx, __shfl_xor(mx, o));
    float ex = (lane < 47) ? __expf(u - mx) : 0.f;
    float sm = ex;
#pragma unroll
    for (int o = 32; o > 0; o >>= 1) sm += __shfl_xor(sm, o);
    if (lane < 47) out[(size_t)n * 47 + lane] = u - mx - logf(sm);
}

// ---------------- launch ----------------

extern "C" void kernel_launch(void* const* d_in, const int* in_sizes, int n_in,
                              void* d_out, int out_size, void* d_ws, size_t ws_size,
                              hipStream_t stream) {
    const float* x = (const float*)d_in[0];
    const int* src = (const int*)d_in[1];
    const int* dst = (const int*)d_in[2];
    const float* W1 = (const float*)d_in[3];
    const float* al1 = (const float*)d_in[4];
    const float* ar1 = (const float*)d_in[5];
    const float* W2 = (const float*)d_in[6];
    const float* al2 = (const float*)d_in[7];
    const float* ar2 = (const float*)d_in[8];
    const float* W3 = (const float*)d_in[9];
    const float* al3 = (const float*)d_in[10];
    const float* ar3 = (const float*)d_in[11];
    float* out = (float*)d_out;

    char* p = (char*)d_ws;
    auto alloc = [&](size_t bytes) {
        char* r = p;
        p += (bytes + 255) & ~(size_t)255;
        return r;
    };
    u16* bufA = (u16*)alloc((size_t)N_NODES * 128 * 2);
    u16* bufC = (u16*)alloc((size_t)N_NODES * 128 * 2);
    u16* featb = (u16*)alloc((size_t)N_NODES * 192 * 2);
    float* el = (float*)alloc((size_t)N_NODES * NH * 4);
    float* er = (float*)alloc((size_t)N_NODES * NH * 4);
    u16* wp1 = (u16*)alloc((size_t)32768 * 2);
    u16* wp2 = (u16*)alloc((size_t)16384 * 2);
    u16* wp3 = (u16*)alloc((size_t)24576 * 2);
    int* deg = (int*)alloc((size_t)N_NODES * 4);
    int* offs = (int*)alloc((size_t)(N_NODES + 1) * 4);
    int* cursor = (int*)alloc((size_t)N_NODES * 4);
    int* bsum = (int*)alloc(64 * 4);
    int* csrc = (int*)alloc((size_t)N_EDGES * 4);

    // fused W pre-pack (one dispatch)
    prep_all<<<288, 256, 0, stream>>>(W1, W2, W3, wp1, wp2, wp3);

    // CSR by dst (scan2 fused into scan3)
    hipMemsetAsync(deg, 0, (size_t)N_NODES * 4, stream);
    k_hist<<<(N_EDGES + 255) / 256, 256, 0, stream>>>(dst, deg);
    k_scan1<<<49, 1024, 0, stream>>>(deg, offs, bsum);
    k_scan3<<<49, 1024, 0, stream>>>(offs, bsum, cursor, 49);
    k_scatter<<<(N_EDGES + 255) / 256, 256, 0, stream>>>(src, dst, cursor, csrc);

    int gemm_grid = (N_NODES + 63) / 64;
    // layer 1
    gemm_mfma<256, 128, 128, true, true, false><<<gemm_grid, 256, 0, stream>>>(x, wp1, featb, al1, ar1, el, er);
    gat_agg128<<<N_NODES / 4, 256, 0, stream>>>(featb, el, er, offs, csrc, bufA);
    // layer 2
    gemm_mfma<128, 128, 128, false, true, false><<<gemm_grid, 256, 0, stream>>>(bufA, wp2, featb, al2, ar2, el, er);
    gat_agg128<<<N_NODES / 4, 256, 0, stream>>>(featb, el, er, offs, csrc, bufC);
    // layer 3 (head-major-48 padded layout; dots fused)
    gemm_mfma<128, 192, 192, false, true, true><<<gemm_grid, 256, 0, stream>>>(bufC, wp3, featb, al3, ar3, el, er);
    gat_agg_final<<<N_NODES / 4, 256, 0, stream>>>(featb, el, er, offs, csrc, out);
}